// Round 3
// baseline (724.518 us; speedup 1.0000x reference)
//
#include <hip/hip_runtime.h>
#include <hip/hip_bf16.h>

using bf16 = __hip_bfloat16;
typedef __attribute__((ext_vector_type(8))) short short8;
typedef __attribute__((ext_vector_type(4))) float floatx4;

// ---- dtype helpers: inputs are fp32 (per reference), MFMA wants bf16 ------
__device__ __forceinline__ short f2b(float x) {
  union { bf16 h; short s; } u;
  u.h = __float2bfloat16(x);
  return u.s;
}
__device__ __forceinline__ short8 ld8(const bf16* p) {
  return *(const short8*)p;
}
__device__ __forceinline__ short8 ld8(const float* p) {
  const floatx4 a = *(const floatx4*)p;
  const floatx4 b = *(const floatx4*)(p + 4);
  short8 r;
  r[0] = f2b(a[0]); r[1] = f2b(a[1]); r[2] = f2b(a[2]); r[3] = f2b(a[3]);
  r[4] = f2b(b[0]); r[5] = f2b(b[1]); r[6] = f2b(b[2]); r[7] = f2b(b[3]);
  return r;
}
__device__ __forceinline__ void st(float* p, float v) { *p = v; }
__device__ __forceinline__ void st(bf16* p, float v) { *p = __float2bfloat16(v); }

// ---------------------------------------------------------------------------
// GEMM: C[M,N] = A[M,K] * B[N,K]^T  (bf16 MFMA, fp32 accum), dtype-templated.
// 128x128 tile, 4 waves, 16x16x32 bf16 MFMA, BK=32. Explicit VGPR staging
// with on-the-fly fp32->bf16 convert.
// ---------------------------------------------------------------------------
template <typename TA, typename TB, typename TC>
__global__ __launch_bounds__(256) void gemm_bt(
    const TA* __restrict__ A, const TB* __restrict__ B,
    TC* __restrict__ C, int M, int N, int K)
{
  __shared__ bf16 As[128 * 32];
  __shared__ bf16 Bs[128 * 32];

  const int tid  = threadIdx.x;
  const int wave = tid >> 6;
  const int lane = tid & 63;
  const int quad = lane >> 4;
  const int l16  = lane & 15;

  const long m0 = (long)blockIdx.x * 128;
  const long n0 = (long)blockIdx.y * 128;
  const int  wr = (wave >> 1) * 64;   // wave row origin in tile
  const int  wc = (wave & 1) * 64;    // wave col origin in tile

  // staging map: chunk c = tid + it*256, row = c>>2 (0..127), col = (c&3)*8
  const int r0 = tid >> 2;
  const int c0 = (tid & 3) * 8;

  floatx4 acc[4][4];
#pragma unroll
  for (int mi = 0; mi < 4; mi++)
#pragma unroll
    for (int ni = 0; ni < 4; ni++) {
      floatx4 z = {0.f, 0.f, 0.f, 0.f};
      acc[mi][ni] = z;
    }

  for (int k0 = 0; k0 < K; k0 += 32) {
    short8 av[2], bv[2];
#pragma unroll
    for (int it = 0; it < 2; it++) {
      const int row = r0 + it * 64;
      av[it] = ld8(A + (m0 + row) * (long)K + k0 + c0);
      bv[it] = ld8(B + (n0 + row) * (long)K + k0 + c0);
    }
    __syncthreads();   // previous iteration's LDS reads complete
#pragma unroll
    for (int it = 0; it < 2; it++) {
      const int row = r0 + it * 64;
      *(short8*)(As + row * 32 + c0) = av[it];
      *(short8*)(Bs + row * 32 + c0) = bv[it];
    }
    __syncthreads();

    short8 a[4], b[4];
#pragma unroll
    for (int i = 0; i < 4; i++) {
      a[i] = *(const short8*)(As + (wr + i * 16 + l16) * 32 + quad * 8);
      b[i] = *(const short8*)(Bs + (wc + i * 16 + l16) * 32 + quad * 8);
    }
#pragma unroll
    for (int mi = 0; mi < 4; mi++)
#pragma unroll
      for (int ni = 0; ni < 4; ni++)
        acc[mi][ni] = __builtin_amdgcn_mfma_f32_16x16x32_bf16(
            a[mi], b[ni], acc[mi][ni], 0, 0, 0);
  }

  // epilogue: C/D layout col = lane&15, row = quad*4 + reg
#pragma unroll
  for (int mi = 0; mi < 4; mi++) {
#pragma unroll
    for (int ni = 0; ni < 4; ni++) {
      floatx4 v = acc[mi][ni];
      const long row = m0 + wr + mi * 16 + quad * 4;
      const long col = n0 + wc + ni * 16 + l16;
#pragma unroll
      for (int r = 0; r < 4; r++)
        st(&C[(row + r) * (long)N + col], v[r]);
    }
  }
}

// ---------------------------------------------------------------------------
// RoPE (interleaved pairs), in-place on bf16 q and k. Layout (B,S,H,hd).
// ---------------------------------------------------------------------------
__global__ void rope_kernel(bf16* __restrict__ q, bf16* __restrict__ k,
                            int total, int S)
{
  int t = blockIdx.x * blockDim.x + threadIdx.x;
  if (t >= 2 * total) return;
  bf16* buf = (t < total) ? q : k;
  int i = (t < total) ? t : t - total;

  const int p = i & 63;                   // pair index within head (hd=128)
  const int s = (i >> 10) % S;            // (i>>6)/H = b*S + s  (H=16)
  const long base = ((long)(i >> 6)) * 128 + 2 * p;

  // inv_freq = 10000^(-2p/128) = 2^(-p/64 * log2(10000))
  const float inv_freq = exp2f(-(float)p * (13.287712379549449f / 64.0f));
  const float angle = (float)s * inv_freq;
  float sn, cs;
  __sincosf(angle, &sn, &cs);

  const float xr = __bfloat162float(buf[base]);
  const float xi = __bfloat162float(buf[base + 1]);
  buf[base]     = __float2bfloat16(xr * cs - xi * sn);
  buf[base + 1] = __float2bfloat16(xr * sn + xi * cs);
}

// ---------------------------------------------------------------------------
// Causal flash attention (bf16 in/out, fp32 softmax/accum). One block =
// one (b,h) x 64 Q rows; 4 waves, each owns 16 rows. hd=128, Bc=64.
// ---------------------------------------------------------------------------
#define NEG_BIG (-30000.0f)

__global__ __launch_bounds__(256) void flash_attn(
    const bf16* __restrict__ q, const bf16* __restrict__ k,
    const bf16* __restrict__ v, bf16* __restrict__ o, int S)
{
  __shared__ bf16 Ks[64 * 136];     // K tile row-major, padded rows
  __shared__ bf16 Vt[128 * 72];     // V tile transposed: Vt[d][kv]
  __shared__ bf16 Ps[4][16 * 72];   // per-wave P scratch

  const int tid  = threadIdx.x;
  const int wave = tid >> 6;
  const int lane = tid & 63;
  const int quad = lane >> 4;
  const int l16  = lane & 15;

  const int bh = blockIdx.y;          // b*H + h
  const int b  = bh >> 4, h = bh & 15;
  const int q0 = blockIdx.x * 64;

  const bf16* Qb = q + ((long)b * S * 16 + h) * 128;
  const bf16* Kb = k + ((long)b * S * 16 + h) * 128;
  const bf16* Vb = v + ((long)b * S * 16 + h) * 128;
  bf16*       Ob = o + ((long)b * S * 16 + h) * 128;

  const long qrow = q0 + wave * 16 + l16;
  short8 aq[4];
#pragma unroll
  for (int kt = 0; kt < 4; kt++)
    aq[kt] = *(const short8*)(Qb + qrow * 2048 + kt * 32 + quad * 8);

  float m_i[4], l_i[4];
  floatx4 oacc[8];
  const floatx4 zero4 = {0.f, 0.f, 0.f, 0.f};
#pragma unroll
  for (int r = 0; r < 4; r++) { m_i[r] = NEG_BIG; l_i[r] = 0.f; }
#pragma unroll
  for (int dt = 0; dt < 8; dt++) oacc[dt] = zero4;

  const float scale = 0.08838834764831845f;   // 1/sqrt(128)

  for (int kt0 = 0; kt0 <= q0; kt0 += 64) {
    __syncthreads();

    // stage K tile: row-major, coalesced 16B loads
#pragma unroll
    for (int it = 0; it < 4; it++) {
      const int chunk = tid + it * 256;
      const int row = chunk >> 4;
      const int d0  = (chunk & 15) * 8;
      short8 val = *(const short8*)(Kb + (long)(kt0 + row) * 2048 + d0);
      *(short8*)(Ks + row * 136 + d0) = val;
    }
    // stage V transposed
#pragma unroll
    for (int it = 0; it < 4; it++) {
      const int chunk = tid + it * 256;
      const int row = chunk & 63;
      const int d0  = (chunk >> 6) * 8;
      short8 val = *(const short8*)(Vb + (long)(kt0 + row) * 2048 + d0);
      const short* vs = (const short*)&val;
#pragma unroll
      for (int j = 0; j < 8; j++)
        *(short*)(Vt + (d0 + j) * 72 + row) = vs[j];
    }
    __syncthreads();

    // S = Q K^T (16 x 64 per wave)
    floatx4 sc[4];
#pragma unroll
    for (int nt = 0; nt < 4; nt++) {
      floatx4 a = zero4;
#pragma unroll
      for (int kt = 0; kt < 4; kt++) {
        short8 bk = *(const short8*)(Ks + (nt * 16 + l16) * 136 + kt * 32 + quad * 8);
        a = __builtin_amdgcn_mfma_f32_16x16x32_bf16(aq[kt], bk, a, 0, 0, 0);
      }
      sc[nt] = a;
    }

    // mask + scale + online softmax
    float alpha[4];
#pragma unroll
    for (int r = 0; r < 4; r++) {
      const int qr = q0 + wave * 16 + quad * 4 + r;
      float mx = NEG_BIG;
#pragma unroll
      for (int nt = 0; nt < 4; nt++) {
        const int kc = kt0 + nt * 16 + l16;
        float vsc = sc[nt][r] * scale;
        vsc = (kc <= qr) ? vsc : NEG_BIG;
        sc[nt][r] = vsc;
        mx = fmaxf(mx, vsc);
      }
      mx = fmaxf(mx, __shfl_xor(mx, 1));
      mx = fmaxf(mx, __shfl_xor(mx, 2));
      mx = fmaxf(mx, __shfl_xor(mx, 4));
      mx = fmaxf(mx, __shfl_xor(mx, 8));
      const float mnew = fmaxf(m_i[r], mx);

      alpha[r] = __expf(m_i[r] - mnew);
      float rs = 0.f;
#pragma unroll
      for (int nt = 0; nt < 4; nt++) {
        float p = __expf(sc[nt][r] - mnew);
        sc[nt][r] = p;
        rs += p;
      }
      rs += __shfl_xor(rs, 1);
      rs += __shfl_xor(rs, 2);
      rs += __shfl_xor(rs, 4);
      rs += __shfl_xor(rs, 8);
      l_i[r] = l_i[r] * alpha[r] + rs;
      m_i[r] = mnew;
    }

    // P: C-layout -> A-layout via per-wave LDS round-trip
#pragma unroll
    for (int nt = 0; nt < 4; nt++)
#pragma unroll
      for (int r = 0; r < 4; r++)
        Ps[wave][(quad * 4 + r) * 72 + nt * 16 + l16] = __float2bfloat16(sc[nt][r]);

    // rescale O accumulator
#pragma unroll
    for (int dt = 0; dt < 8; dt++)
#pragma unroll
      for (int r = 0; r < 4; r++)
        oacc[dt][r] *= alpha[r];

    // O += P V
#pragma unroll
    for (int ks = 0; ks < 2; ks++) {
      short8 ap = *(const short8*)(&Ps[wave][l16 * 72 + ks * 32 + quad * 8]);
#pragma unroll
      for (int dt = 0; dt < 8; dt++) {
        short8 bv = *(const short8*)(Vt + (dt * 16 + l16) * 72 + ks * 32 + quad * 8);
        oacc[dt] = __builtin_amdgcn_mfma_f32_16x16x32_bf16(ap, bv, oacc[dt], 0, 0, 0);
      }
    }
  }

  // epilogue: O / l
#pragma unroll
  for (int r = 0; r < 4; r++) {
    const float inv = 1.0f / l_i[r];
    const long s = q0 + wave * 16 + quad * 4 + r;
#pragma unroll
    for (int dt = 0; dt < 8; dt++)
      Ob[s * 2048 + dt * 16 + l16] = __float2bfloat16(oacc[dt][r] * inv);
  }
}

// ---------------------------------------------------------------------------
extern "C" void kernel_launch(void* const* d_in, const int* in_sizes, int n_in,
                              void* d_out, int out_size, void* d_ws, size_t ws_size,
                              hipStream_t stream) {
  // Reference dtypes: ALL inputs float32, output float32.
  const float* x  = (const float*)d_in[0];
  const float* wq = (const float*)d_in[1];
  const float* wk = (const float*)d_in[2];
  const float* wv = (const float*)d_in[3];
  const float* wo = (const float*)d_in[4];
  float* out = (float*)d_out;

  const int B = 2, S = 2048, D = 2048, H = 16;
  const int M = B * S;                    // 4096
  const size_t tsz = (size_t)M * D;       // elements per intermediate

  if (ws_size < 4 * tsz * sizeof(bf16)) return;   // need 67 MB

  bf16* qb = (bf16*)d_ws;
  bf16* kb = qb + tsz;
  bf16* vb = kb + tsz;
  bf16* ab = vb + tsz;

  dim3 gg(M / 128, D / 128);              // (32, 16)
  gemm_bt<float, float, bf16><<<gg, 256, 0, stream>>>(x, wq, qb, M, D, D);
  gemm_bt<float, float, bf16><<<gg, 256, 0, stream>>>(x, wk, kb, M, D, D);
  gemm_bt<float, float, bf16><<<gg, 256, 0, stream>>>(x, wv, vb, M, D, D);

  const int total = M * H * 64;           // B*S*H*(hd/2) pairs per tensor
  rope_kernel<<<(2 * total + 255) / 256, 256, 0, stream>>>(qb, kb, total, S);

  flash_attn<<<dim3(S / 64, B * H), 256, 0, stream>>>(qb, kb, vb, ab, S);

  gemm_bt<bf16, float, float><<<gg, 256, 0, stream>>>(ab, wo, out, M, D, D);
}

// Round 4
// 534.268 us; speedup vs baseline: 1.3561x; 1.3561x over previous
//
#include <hip/hip_runtime.h>
#include <hip/hip_bf16.h>

using bf16 = __hip_bfloat16;
typedef __attribute__((ext_vector_type(8))) short short8;
typedef __attribute__((ext_vector_type(4))) float floatx4;

#define GLDS16(g, l)                                                        \
  __builtin_amdgcn_global_load_lds(                                         \
      (const __attribute__((address_space(1))) void*)(g),                   \
      (__attribute__((address_space(3))) void*)(l), 16, 0, 0)

__device__ __forceinline__ short f2b(float x) {
  union { bf16 h; short s; } u;
  u.h = __float2bfloat16(x);
  return u.s;
}
__device__ __forceinline__ void st(float* p, float v) { *p = v; }
__device__ __forceinline__ void st(bf16* p, float v) { *p = __float2bfloat16(v); }

// ---------------------------------------------------------------------------
// fp32 -> bf16 cast, 8 elems/thread, fully coalesced.
// ---------------------------------------------------------------------------
__global__ void cast_kernel(const float* __restrict__ in, bf16* __restrict__ out,
                            long n) {
  long i = ((long)blockIdx.x * blockDim.x + threadIdx.x) * 8;
  if (i >= n) return;
  floatx4 a = *(const floatx4*)(in + i);
  floatx4 b = *(const floatx4*)(in + i + 4);
  short8 r;
  r[0] = f2b(a[0]); r[1] = f2b(a[1]); r[2] = f2b(a[2]); r[3] = f2b(a[3]);
  r[4] = f2b(b[0]); r[5] = f2b(b[1]); r[6] = f2b(b[2]); r[7] = f2b(b[3]);
  *(short8*)(out + i) = r;
}

// ---------------------------------------------------------------------------
// GEMM: C[M,N] = A[M,K] * B[N,K]^T  (bf16 in, fp32 accum, TC out)
// m97 structure: 128x128 tile, 4 waves, 16x16x32 MFMA, BK=32,
// global_load_lds width=16 staging, 2-barrier K-loop.
// ---------------------------------------------------------------------------
template <typename TC>
__global__ __launch_bounds__(256) void gemm_bt(
    const bf16* __restrict__ A, const bf16* __restrict__ B,
    TC* __restrict__ C, int M, int N, int K)
{
  __shared__ bf16 As[128 * 32];
  __shared__ bf16 Bs[128 * 32];

  const int tid  = threadIdx.x;
  const int wave = tid >> 6;
  const int lane = tid & 63;
  const int quad = lane >> 4;
  const int l16  = lane & 15;

  const long m0 = (long)blockIdx.x * 128;
  const long n0 = (long)blockIdx.y * 128;
  const int  wr = (wave >> 1) * 64;
  const int  wc = (wave & 1) * 64;

  // staging: wave covers rows [wave*32, wave*32+32); lane l handles
  // row wave*32 + (l>>2), cols (l&3)*8..+8  -> LDS offset = base + l*16B
  const int srow = wave * 32 + (lane >> 2);
  const int scol = (lane & 3) * 8;
  const bf16* Ag = A + (m0 + srow) * (long)K + scol;
  const bf16* Bg = B + (n0 + srow) * (long)K + scol;
  bf16* AsB = As + wave * 1024;   // wave-uniform LDS bases
  bf16* BsB = Bs + wave * 1024;

  floatx4 acc[4][4];
#pragma unroll
  for (int mi = 0; mi < 4; mi++)
#pragma unroll
    for (int ni = 0; ni < 4; ni++) {
      floatx4 z = {0.f, 0.f, 0.f, 0.f};
      acc[mi][ni] = z;
    }

  for (int k0 = 0; k0 < K; k0 += 32) {
    GLDS16(Ag + k0,                AsB);
    GLDS16(Ag + 16 * (long)K + k0, AsB + 512);
    GLDS16(Bg + k0,                BsB);
    GLDS16(Bg + 16 * (long)K + k0, BsB + 512);
    __syncthreads();   // compiler drains vmcnt before s_barrier

    short8 a[4], b[4];
#pragma unroll
    for (int i = 0; i < 4; i++) {
      a[i] = *(const short8*)(As + (wr + i * 16 + l16) * 32 + quad * 8);
      b[i] = *(const short8*)(Bs + (wc + i * 16 + l16) * 32 + quad * 8);
    }
#pragma unroll
    for (int mi = 0; mi < 4; mi++)
#pragma unroll
      for (int ni = 0; ni < 4; ni++)
        acc[mi][ni] = __builtin_amdgcn_mfma_f32_16x16x32_bf16(
            a[mi], b[ni], acc[mi][ni], 0, 0, 0);
    __syncthreads();   // protect LDS before next stage
  }

  // epilogue: C/D layout col = lane&15, row = quad*4 + reg
#pragma unroll
  for (int mi = 0; mi < 4; mi++) {
#pragma unroll
    for (int ni = 0; ni < 4; ni++) {
      floatx4 v = acc[mi][ni];
      const long row = m0 + wr + mi * 16 + quad * 4;
      const long col = n0 + wc + ni * 16 + l16;
#pragma unroll
      for (int r = 0; r < 4; r++)
        st(&C[(row + r) * (long)N + col], v[r]);
    }
  }
}

// ---------------------------------------------------------------------------
// RoPE (interleaved pairs), in-place on bf16 q and k. Layout (B,S,H,hd).
// ---------------------------------------------------------------------------
__global__ void rope_kernel(bf16* __restrict__ q, bf16* __restrict__ k,
                            int total, int S)
{
  int t = blockIdx.x * blockDim.x + threadIdx.x;
  if (t >= 2 * total) return;
  bf16* buf = (t < total) ? q : k;
  int i = (t < total) ? t : t - total;

  const int p = i & 63;                   // pair index within head (hd=128)
  const int s = (i >> 10) % S;            // (i>>6)/H = b*S + s  (H=16)
  const long base = ((long)(i >> 6)) * 128 + 2 * p;

  const float inv_freq = exp2f(-(float)p * (13.287712379549449f / 64.0f));
  const float angle = (float)s * inv_freq;
  float sn, cs;
  __sincosf(angle, &sn, &cs);

  const float xr = __bfloat162float(buf[base]);
  const float xi = __bfloat162float(buf[base + 1]);
  buf[base]     = __float2bfloat16(xr * cs - xi * sn);
  buf[base + 1] = __float2bfloat16(xr * sn + xi * cs);
}

// ---------------------------------------------------------------------------
// Causal flash attention. Q-tile 128 rows/block (wave owns 32 rows = two
// 16-row frags), K-tile 64, hd=128. Heavy q-tiles dispatched first
// (q0 reversed in blockIdx.y). Fully-masked diagonal tiles skipped
// wave-uniformly. V transposed into LDS via paired-kv b32 writes.
// ---------------------------------------------------------------------------
#define NEG_BIG (-30000.0f)

__global__ __launch_bounds__(256) void flash_attn(
    const bf16* __restrict__ q, const bf16* __restrict__ k,
    const bf16* __restrict__ v, bf16* __restrict__ o, int S)
{
  __shared__ bf16 Ks[64 * 136];      // K tile row-major, stride 136
  __shared__ bf16 Vt[128 * 72];      // V^T: Vt[d][kv], stride 72
  __shared__ bf16 Ps[4][32 * 72];    // per-wave P scratch (32 rows)

  const int tid  = threadIdx.x;
  const int wave = tid >> 6;
  const int lane = tid & 63;
  const int quad = lane >> 4;
  const int l16  = lane & 15;

  const int bh = blockIdx.x;          // b*H + h   (x = bh for balance pairing)
  const int b  = bh >> 4, h = bh & 15;
  const int q0 = ((int)gridDim.y - 1 - (int)blockIdx.y) * 128;  // heavy first

  const bf16* Qb = q + ((long)b * S * 16 + h) * 128;
  const bf16* Kb = k + ((long)b * S * 16 + h) * 128;
  const bf16* Vb = v + ((long)b * S * 16 + h) * 128;
  bf16*       Ob = o + ((long)b * S * 16 + h) * 128;

  // Q fragments: A[m=l16][k = kt*32 + quad*8 + j], rows wave*32 + mi*16 + l16
  short8 aq[2][4];
#pragma unroll
  for (int mi = 0; mi < 2; mi++)
#pragma unroll
    for (int kt = 0; kt < 4; kt++)
      aq[mi][kt] = *(const short8*)(
          Qb + (long)(q0 + wave * 32 + mi * 16 + l16) * 2048 + kt * 32 + quad * 8);

  float m_i[2][4], l_i[2][4];
  floatx4 oacc[2][8];
  const floatx4 zero4 = {0.f, 0.f, 0.f, 0.f};
#pragma unroll
  for (int mi = 0; mi < 2; mi++) {
#pragma unroll
    for (int r = 0; r < 4; r++) { m_i[mi][r] = NEG_BIG; l_i[mi][r] = 0.f; }
#pragma unroll
    for (int dt = 0; dt < 8; dt++) oacc[mi][dt] = zero4;
  }

  const float scale = 0.08838834764831845f;   // 1/sqrt(128)
  const int wrow0 = q0 + wave * 32;           // wave's lowest Q row

  for (int kt0 = 0; kt0 < q0 + 128; kt0 += 64) {
    __syncthreads();   // previous iteration's LDS reads complete

    // ---- stage K: row-major, coalesced b128 ----
#pragma unroll
    for (int it = 0; it < 4; it++) {
      const int c = tid + it * 256;
      const int row = c >> 4;                 // 0..63
      const int d0  = (c & 15) * 8;
      *(short8*)(Ks + row * 136 + d0) =
          *(const short8*)(Kb + (long)(kt0 + row) * 2048 + d0);
    }
    // ---- stage V^T: paired kv rows -> b32 LDS writes (2-way banks, free) ----
#pragma unroll
    for (int it = 0; it < 2; it++) {
      const int c = tid + it * 256;           // 0..511
      const int d0 = (c >> 5) * 8;            // 0..120
      const int rp = (c & 31) * 2;            // kv row pair
      short8 v0 = *(const short8*)(Vb + (long)(kt0 + rp) * 2048 + d0);
      short8 v1 = *(const short8*)(Vb + (long)(kt0 + rp + 1) * 2048 + d0);
#pragma unroll
      for (int j = 0; j < 8; j++) {
        unsigned int w = (unsigned short)v0[j] | ((unsigned int)(unsigned short)v1[j] << 16);
        *(unsigned int*)(Vt + (d0 + j) * 72 + rp) = w;
      }
    }
    __syncthreads();

    if (kt0 <= wrow0 + 31) {   // wave-uniform: skip fully-masked tiles
      // ---- S = Q K^T : 32 rows x 64 cols per wave ----
      floatx4 sc[2][4];
#pragma unroll
      for (int mi = 0; mi < 2; mi++)
#pragma unroll
        for (int nt = 0; nt < 4; nt++) sc[mi][nt] = zero4;
#pragma unroll
      for (int nt = 0; nt < 4; nt++)
#pragma unroll
        for (int kt = 0; kt < 4; kt++) {
          short8 bk = *(const short8*)(Ks + (nt * 16 + l16) * 136 + kt * 32 + quad * 8);
          sc[0][nt] = __builtin_amdgcn_mfma_f32_16x16x32_bf16(aq[0][kt], bk, sc[0][nt], 0, 0, 0);
          sc[1][nt] = __builtin_amdgcn_mfma_f32_16x16x32_bf16(aq[1][kt], bk, sc[1][nt], 0, 0, 0);
        }

      const bool needmask = (kt0 + 63 > wrow0);
      float alpha[2][4];
#pragma unroll
      for (int mi = 0; mi < 2; mi++) {
#pragma unroll
        for (int r = 0; r < 4; r++) {
          const int qr = wrow0 + mi * 16 + quad * 4 + r;
          float mx = NEG_BIG;
          if (needmask) {
#pragma unroll
            for (int nt = 0; nt < 4; nt++) {
              const int kc = kt0 + nt * 16 + l16;
              float vsc = sc[mi][nt][r] * scale;
              vsc = (kc <= qr) ? vsc : NEG_BIG;
              sc[mi][nt][r] = vsc;
              mx = fmaxf(mx, vsc);
            }
          } else {
#pragma unroll
            for (int nt = 0; nt < 4; nt++) {
              float vsc = sc[mi][nt][r] * scale;
              sc[mi][nt][r] = vsc;
              mx = fmaxf(mx, vsc);
            }
          }
          mx = fmaxf(mx, __shfl_xor(mx, 1));
          mx = fmaxf(mx, __shfl_xor(mx, 2));
          mx = fmaxf(mx, __shfl_xor(mx, 4));
          mx = fmaxf(mx, __shfl_xor(mx, 8));
          const float mnew = fmaxf(m_i[mi][r], mx);

          alpha[mi][r] = __expf(m_i[mi][r] - mnew);
          float rs = 0.f;
#pragma unroll
          for (int nt = 0; nt < 4; nt++) {
            float p = __expf(sc[mi][nt][r] - mnew);
            sc[mi][nt][r] = p;
            rs += p;
          }
          rs += __shfl_xor(rs, 1);
          rs += __shfl_xor(rs, 2);
          rs += __shfl_xor(rs, 4);
          rs += __shfl_xor(rs, 8);
          l_i[mi][r] = l_i[mi][r] * alpha[mi][r] + rs;
          m_i[mi][r] = mnew;
        }
      }

      // ---- P: C-layout -> A-layout via per-wave LDS round-trip ----
#pragma unroll
      for (int mi = 0; mi < 2; mi++)
#pragma unroll
        for (int nt = 0; nt < 4; nt++)
#pragma unroll
          for (int r = 0; r < 4; r++)
            Ps[wave][(mi * 16 + quad * 4 + r) * 72 + nt * 16 + l16] =
                __float2bfloat16(sc[mi][nt][r]);

      // rescale O accumulator
#pragma unroll
      for (int mi = 0; mi < 2; mi++)
#pragma unroll
        for (int dt = 0; dt < 8; dt++)
#pragma unroll
          for (int r = 0; r < 4; r++)
            oacc[mi][dt][r] *= alpha[mi][r];

      // ---- O += P V ----
#pragma unroll
      for (int ks = 0; ks < 2; ks++) {
        short8 ap0 = *(const short8*)(&Ps[wave][(l16) * 72 + ks * 32 + quad * 8]);
        short8 ap1 = *(const short8*)(&Ps[wave][(16 + l16) * 72 + ks * 32 + quad * 8]);
#pragma unroll
        for (int dt = 0; dt < 8; dt++) {
          short8 bv = *(const short8*)(Vt + (dt * 16 + l16) * 72 + ks * 32 + quad * 8);
          oacc[0][dt] = __builtin_amdgcn_mfma_f32_16x16x32_bf16(ap0, bv, oacc[0][dt], 0, 0, 0);
          oacc[1][dt] = __builtin_amdgcn_mfma_f32_16x16x32_bf16(ap1, bv, oacc[1][dt], 0, 0, 0);
        }
      }
    }
  }

  // ---- epilogue: O / l ----
#pragma unroll
  for (int mi = 0; mi < 2; mi++)
#pragma unroll
    for (int r = 0; r < 4; r++) {
      const float inv = 1.0f / l_i[mi][r];
      const long s = q0 + wave * 32 + mi * 16 + quad * 4 + r;
#pragma unroll
      for (int dt = 0; dt < 8; dt++)
        Ob[s * 2048 + dt * 16 + l16] = __float2bfloat16(oacc[mi][dt][r] * inv);
    }
}

// ---------------------------------------------------------------------------
extern "C" void kernel_launch(void* const* d_in, const int* in_sizes, int n_in,
                              void* d_out, int out_size, void* d_ws, size_t ws_size,
                              hipStream_t stream) {
  const float* x  = (const float*)d_in[0];
  const float* wq = (const float*)d_in[1];
  const float* wk = (const float*)d_in[2];
  const float* wv = (const float*)d_in[3];
  const float* wo = (const float*)d_in[4];
  float* out = (float*)d_out;

  const int B = 2, S = 2048, D = 2048, H = 16;
  const int M = B * S;                    // 4096
  const long tsz = (long)M * D;           // 8.39M elems per intermediate
  const long wsz = (long)D * D;           // 4.19M elems per weight

  if (ws_size < 4 * (size_t)tsz * sizeof(bf16)) return;   // 67 MB

  // ws: bf16 intermediates
  bf16* qb = (bf16*)d_ws;
  bf16* kb = qb + tsz;
  bf16* vb = kb + tsz;
  bf16* ab = vb + tsz;

  // d_out doubles as scratch for bf16 casts of x and the current weight
  // (xb: [0,16.8MB), wb: [16.8,25.2MB) of the 33.6MB output buffer; both
  // dead before the final GEMM overwrites d_out).
  bf16* xb = (bf16*)d_out;
  bf16* wb = xb + tsz;
  bf16* wob = qb;    // qb is dead after flash_attn; reuse for wo

  dim3 gg(M / 128, D / 128);              // (32, 16)

  cast_kernel<<<(int)(tsz / 8 / 256), 256, 0, stream>>>(x, xb, tsz);

  cast_kernel<<<(int)(wsz / 8 / 256), 256, 0, stream>>>(wq, wb, wsz);
  gemm_bt<bf16><<<gg, 256, 0, stream>>>(xb, wb, qb, M, D, D);
  cast_kernel<<<(int)(wsz / 8 / 256), 256, 0, stream>>>(wk, wb, wsz);
  gemm_bt<bf16><<<gg, 256, 0, stream>>>(xb, wb, kb, M, D, D);
  cast_kernel<<<(int)(wsz / 8 / 256), 256, 0, stream>>>(wv, wb, wsz);
  gemm_bt<bf16><<<gg, 256, 0, stream>>>(xb, wb, vb, M, D, D);

  const int total = M * H * 64;           // pairs per tensor
  rope_kernel<<<(2 * total + 255) / 256, 256, 0, stream>>>(qb, kb, total, S);

  flash_attn<<<dim3(B * H, S / 128), 256, 0, stream>>>(qb, kb, vb, ab, S);

  cast_kernel<<<(int)(wsz / 8 / 256), 256, 0, stream>>>(wo, wob, wsz);
  gemm_bt<float><<<gg, 256, 0, stream>>>(ab, wob, out, M, D, D);
}